// Round 10
// baseline (5786.167 us; speedup 1.0000x reference)
//
#include <hip/hip_runtime.h>

typedef unsigned short u16;
typedef unsigned long long u64;
using short8 = __attribute__((ext_vector_type(8))) short;
using f32x4  = __attribute__((ext_vector_type(4))) float;

#define GF_RELU  1
#define GF_F32   2
#define GF_XPOSE 4

__device__ __forceinline__ float b2f(u16 x) {
    unsigned u = ((unsigned)x) << 16;
    return __builtin_bit_cast(float, u);
}
__device__ __forceinline__ u16 f2b(float f) {
    unsigned u = __builtin_bit_cast(unsigned, f);
    unsigned r = u + 0x7FFFu + ((u >> 16) & 1u);
    return (u16)(r >> 16);
}
__device__ __forceinline__ f32x4 mfma_bf16(uint4 a, uint4 b, f32x4 c) {
    return __builtin_amdgcn_mfma_f32_16x16x32_bf16(
        __builtin_bit_cast(short8, a), __builtin_bit_cast(short8, b), c, 0, 0, 0);
}
__device__ __forceinline__ f32x4 zero4() { f32x4 z = {0.f, 0.f, 0.f, 0.f}; return z; }

// ---------------------------------------------------------------------------
// f32 -> bf16 conversion (grid-stride)
// ---------------------------------------------------------------------------
__global__ __launch_bounds__(256) void cvt_bf16(const float* __restrict__ src,
                                                u16* __restrict__ dst, int n) {
    for (int i = blockIdx.x * 256 + threadIdx.x; i < n; i += gridDim.x * 256)
        dst[i] = f2b(src[i]);
}

// ---------------------------------------------------------------------------
// Pack W_hh / W_ih (f32 in) into unit-major gate order bf16: packed row
// p = unit*4+gate maps to original row gate*512+unit. biasP (f32) = b_ih+b_hh.
// ---------------------------------------------------------------------------
__global__ void pack_params(const float* __restrict__ Whh, const float* __restrict__ Wih,
                            const float* __restrict__ bih, const float* __restrict__ bhh,
                            u16* __restrict__ WhhP, u16* __restrict__ WihP,
                            float* __restrict__ biasP) {
    int p = blockIdx.x;      // 2048
    int t = threadIdx.x;     // 256
    int orig = ((p & 3) << 9) + (p >> 2);
    WhhP[((long)p << 9) + t]       = f2b(Whh[((long)orig << 9) + t]);
    WhhP[((long)p << 9) + 256 + t] = f2b(Whh[((long)orig << 9) + 256 + t]);
    WihP[((long)p << 8) + t]       = f2b(Wih[((long)orig << 8) + t]);
    if (t == 0) biasP[p] = bih[orig] + bhh[orig];
}

// ---------------------------------------------------------------------------
// Generic C = act(A @ B^T + bias) GEMM, 64x128 tile, register-prefetch
// pipeline (tile k+1 global loads issued before tile k MFMAs -> latency
// overlapped). bf16 in, bf16/f32 out. A row-stride = ksplit; k >= ksplit
// reads A2. GF_XPOSE: store C[m=b*1024+t][n] at [t*8+b][n].
// ---------------------------------------------------------------------------
__global__ __launch_bounds__(256) void gemm_bt(
    const u16* __restrict__ A, const u16* __restrict__ A2, int ksplit,
    const u16* __restrict__ B, void* __restrict__ Cout,
    int M, int N, int K,
    long sAb, long sBb, long sCb,
    const float* __restrict__ bias, const float* __restrict__ rowmask, int flags) {
    __shared__ __align__(16) u16 As[64][40];
    __shared__ __align__(16) u16 Bs[128][40];
    const int bz = blockIdx.z;
    const u16* Ab = A + (long)bz * sAb;
    const u16* Bb = B + (long)bz * sBb;
    const int m0 = blockIdx.x << 6, n0 = blockIdx.y << 7;
    const int tid = threadIdx.x;
    const int lane = tid & 63, wave = tid >> 6;
    const int srow = tid >> 2, skc = (tid & 3) << 3;
    const int frm = lane & 15, fq = lane >> 4;

    auto loadA = [&](int ka) -> uint4 {
        const u16* p = (ka < ksplit)
            ? Ab + (long)(m0 + srow) * ksplit + ka
            : A2 + (long)(m0 + srow) * (K - ksplit) + (ka - ksplit);
        return *(const uint4*)p;
    };
    const u16* Brow0 = Bb + (long)(n0 + srow) * K;
    const u16* Brow1 = Bb + (long)(n0 + 64 + srow) * K;

    f32x4 acc[8];
#pragma unroll
    for (int i = 0; i < 8; i++) acc[i] = zero4();

    uint4 a  = loadA(skc);
    uint4 b0 = *(const uint4*)(Brow0 + skc);
    uint4 b1 = *(const uint4*)(Brow1 + skc);

    for (int k0 = 0; k0 < K; k0 += 32) {
        __syncthreads();
        *(uint4*)&As[srow][skc] = a;
        *(uint4*)&Bs[srow][skc] = b0;
        *(uint4*)&Bs[64 + srow][skc] = b1;
        __syncthreads();
        int kn = k0 + 32;
        if (kn < K) {           // prefetch next tile; overlaps MFMAs below
            a  = loadA(kn + skc);
            b0 = *(const uint4*)(Brow0 + kn + skc);
            b1 = *(const uint4*)(Brow1 + kn + skc);
        }
        uint4 af = *(const uint4*)&As[(wave << 4) + frm][fq << 3];
#pragma unroll
        for (int nt = 0; nt < 8; nt++) {
            uint4 bf = *(const uint4*)&Bs[(nt << 4) + frm][fq << 3];
            acc[nt] = mfma_bf16(af, bf, acc[nt]);
        }
    }
#pragma unroll
    for (int nt = 0; nt < 8; nt++) {
        int col = n0 + (nt << 4) + frm;
        float bv = bias ? bias[col] : 0.f;
#pragma unroll
        for (int r = 0; r < 4; r++) {
            int row = m0 + (wave << 4) + (fq << 2) + r;
            float v = acc[nt][r] + bv;
            if (flags & GF_RELU) v = fmaxf(v, 0.f);
            if (rowmask) v *= rowmask[row];
            long orow = (flags & GF_XPOSE) ? (long)((row & 1023) * 8 + (row >> 10))
                                           : (long)row;
            if (flags & GF_F32)
                ((float*)Cout)[(long)bz * sCb + orow * N + col] = v;
            else
                ((u16*)Cout)[(long)bz * sCb + orow * N + col] = f2b(v);
        }
    }
}

// ---------------------------------------------------------------------------
// Persistent LSTM recurrence, 4 parties. 4 WGs x 512 threads (8 waves each,
// 2 waves/SIMD -> up to 512 VGPRs/wave available; weights = 256 VGPRs/lane).
// WG wg owns packed gate-cols [wg*512,+512) = units [wg*128,+128); wave wv
// owns 64 cols (4 n-subtiles). Protocol identical to r6/r9: tag-in-data u64
// atoms {tag=t+1, dword=2 bf16}, relaxed agent scope, parity double-buffer,
// each wave polls its batch-row portion (4 atoms/lane). xproj is [t][b][p].
// ---------------------------------------------------------------------------
__global__ __launch_bounds__(512, 1) void lstm_rec(
    const u16* __restrict__ WhhP, const u16* __restrict__ xproj,
    u16* __restrict__ h, u64* __restrict__ hx) {
    __shared__ float g_lds[8][516];       // [batch][WG-local gate col 0..511]
    __shared__ unsigned hshare[8][260];   // [batch][h dword 0..255]
    const int wg = blockIdx.x;            // 4
    const int tid = threadIdx.x;          // 512
    const int lane = tid & 63, wv = tid >> 6;     // 8 waves
    const int frm = lane & 15, fq = lane >> 4;
    const int mbb = frm & 7;              // A-operand batch row
    const int xb = (fq & 1) << 2;         // batch base for D rows fq*4+r
    const int C0 = (wg << 9) + (wv << 6); // global packed-col base of wave
    const int pb = tid >> 6, pj = tid & 63;  // phase-2: batch, dword idx

    uint4 bfrag[4][16];                   // 256 VGPRs of pinned W_hh
#pragma unroll
    for (int S = 0; S < 4; S++)
#pragma unroll
        for (int kk = 0; kk < 16; kk++)
            bfrag[S][kk] = *(const uint4*)&WhhP[((long)(C0 + (S << 4) + frm) << 9) +
                                                (kk << 5) + (fq << 3)];

    float creg0 = 0.f, creg1 = 0.f;       // cell state: (batch pb, units 2pj, 2pj+1)
    int budget = 1 << 21;                 // poll bailout: guarantees termination

#pragma unroll 1
    for (int t = 0; t < 1024; t++) {
        // prefetch x_proj for this step (time-major: contiguous 32KB block)
        float xp[4][4];
#pragma unroll
        for (int S = 0; S < 4; S++)
#pragma unroll
            for (int r = 0; r < 4; r++)
                xp[S][r] = b2f(xproj[((long)(t * 8 + xb + r) << 11) +
                                     C0 + (S << 4) + frm]);

        f32x4 acc[4];
#pragma unroll
        for (int S = 0; S < 4; S++) acc[S] = zero4();

        if (t > 0) {
            // poll own portion of h(t-1): atoms [wv*256, wv*256+256), 4/lane
            const u64* buf = hx + (((t - 1) & 1) << 11);
            u64 v[4];
            const unsigned want = (unsigned)t;
            while (true) {
#pragma unroll
                for (int j = 0; j < 4; j++)
                    v[j] = __hip_atomic_load(&buf[(wv << 8) + lane + (j << 6)],
                                             __ATOMIC_RELAXED, __HIP_MEMORY_SCOPE_AGENT);
                bool ok = true;
#pragma unroll
                for (int j = 0; j < 4; j++) ok &= ((unsigned)(v[j] >> 32) == want);
                if (__all(ok) || --budget < 0) break;
            }
#pragma unroll
            for (int j = 0; j < 4; j++) {
                int a = (wv << 8) + lane + (j << 6);   // atom = b*256 + d
                hshare[a >> 8][a & 255] = (unsigned)v[j];
            }
            __syncthreads();  // SYNC1: hshare complete
#pragma unroll
            for (int kk = 0; kk < 16; kk++) {
                uint4 af = *(const uint4*)&hshare[mbb][(kk << 4) + (fq << 2)];
                acc[0] = mfma_bf16(af, bfrag[0][kk], acc[0]);
                acc[1] = mfma_bf16(af, bfrag[1][kk], acc[1]);
                acc[2] = mfma_bf16(af, bfrag[2][kk], acc[2]);
                acc[3] = mfma_bf16(af, bfrag[3][kk], acc[3]);
            }
        }

        // phase 1: gate pre-activations to LDS (wave wv: local cols wv*64..+63)
        if (fq < 2) {
#pragma unroll
            for (int S = 0; S < 4; S++)
#pragma unroll
                for (int r = 0; r < 4; r++)
                    g_lds[(fq << 2) + r][(wv << 6) + (S << 4) + frm] = acc[S][r] + xp[S][r];
        }
        __syncthreads();  // SYNC2: g_lds ready

        // phase 2: thread (batch pb, local units 2pj,2pj+1): activations,
        // c-update, publish {tag,2xbf16} + plain h (one dword per thread)
        {
            f32x4 ga = *(const f32x4*)&g_lds[pb][pj << 3];
            f32x4 gb = *(const f32x4*)&g_lds[pb][(pj << 3) + 4];
            float i0 = 1.f / (1.f + __expf(-ga[0]));
            float f0 = 1.f / (1.f + __expf(-ga[1]));
            float c0 = 1.f - 2.f / (__expf(2.f * ga[2]) + 1.f);
            float o0 = 1.f / (1.f + __expf(-ga[3]));
            creg0 = f0 * creg0 + i0 * c0;
            float h0 = o0 * (1.f - 2.f / (__expf(2.f * creg0) + 1.f));
            float i1 = 1.f / (1.f + __expf(-gb[0]));
            float f1 = 1.f / (1.f + __expf(-gb[1]));
            float c1 = 1.f - 2.f / (__expf(2.f * gb[2]) + 1.f);
            float o1 = 1.f / (1.f + __expf(-gb[3]));
            creg1 = f1 * creg1 + i1 * c1;
            float h1 = o1 * (1.f - 2.f / (__expf(2.f * creg1) + 1.f));
            unsigned dw = (unsigned)f2b(h0) | ((unsigned)f2b(h1) << 16);
            ((unsigned*)h)[(((long)(pb * 1024 + t)) << 8) + (wg << 6) + pj] = dw;
            u64 pv = ((u64)(unsigned)(t + 1) << 32) | (u64)dw;
            __hip_atomic_store(&hx[((t & 1) << 11) + (pb << 8) + (wg << 6) + pj], pv,
                               __ATOMIC_RELAXED, __HIP_MEMORY_SCOPE_AGENT);
        }
        // next iteration's SYNC1 guards hshare/g_lds reuse
    }
}

// ---------------------------------------------------------------------------
// h [b][t][u] -> hT [b][u][t]
// ---------------------------------------------------------------------------
__global__ __launch_bounds__(256) void transpose_h(const u16* __restrict__ h,
                                                   u16* __restrict__ hT) {
    __shared__ __align__(16) u16 tile[64][72];
    const int b = blockIdx.z;
    const int t0 = blockIdx.x << 6, u0 = blockIdx.y << 6;
    const int tid = threadIdx.x;
    const int r = tid >> 3, c8 = (tid & 7) << 3;
#pragma unroll
    for (int j = 0; j < 2; j++) {
        int row = r + (j << 5);
        *(uint4*)&tile[row][c8] =
            *(const uint4*)&h[(((long)b << 10) + t0 + row) * 512 + u0 + c8];
    }
    __syncthreads();
#pragma unroll
    for (int j = 0; j < 2; j++) {
        int urow = r + (j << 5);
        unsigned wds[4];
#pragma unroll
        for (int k = 0; k < 4; k++) {
            unsigned lo = tile[c8 + (k << 1)][urow];
            unsigned hi = tile[c8 + (k << 1) + 1][urow];
            wds[k] = lo | (hi << 16);
        }
        uint4 v; v.x = wds[0]; v.y = wds[1]; v.z = wds[2]; v.w = wds[3];
        *(uint4*)&hT[(((long)b << 9) + u0 + urow) * 1024 + t0 + c8] = v;
    }
}

// ---------------------------------------------------------------------------
// Masked softmax over rows of scores [8192][1024]; w = softmax*mask (bf16);
// hasnb = 1.0 if any neighbor else 0.0
// ---------------------------------------------------------------------------
__global__ __launch_bounds__(256) void softmax_row(
    const float* __restrict__ scores, const int* __restrict__ adj,
    u16* __restrict__ w, float* __restrict__ hasnb) {
    __shared__ float red[4];
    const int row = blockIdx.x;  // 8192
    const int i = row & 1023;
    const int tid = threadIdx.x;
    const int lane = tid & 63, wave = tid >> 6;
    const float* s = scores + ((long)row << 10);
    const int* arow = adj + ((long)row << 10);

    float sv[4]; bool mk[4];
    float mx = -3.0e38f;
#pragma unroll
    for (int q = 0; q < 4; q++) {
        int j = tid + (q << 8);
        mk[q] = (arow[j] > 0) && (j != i);
        sv[q] = s[j];
        if (mk[q]) mx = fmaxf(mx, sv[q]);
    }
    for (int off = 32; off; off >>= 1) mx = fmaxf(mx, __shfl_xor(mx, off));
    if (lane == 0) red[wave] = mx;
    __syncthreads();
    mx = fmaxf(fmaxf(red[0], red[1]), fmaxf(red[2], red[3]));
    float e[4]; float sum = 0.f;
#pragma unroll
    for (int q = 0; q < 4; q++) {
        e[q] = mk[q] ? __expf(sv[q] - mx) : 0.f;
        sum += e[q];
    }
    __syncthreads();
    for (int off = 32; off; off >>= 1) sum += __shfl_xor(sum, off);
    if (lane == 0) red[wave] = sum;
    __syncthreads();
    sum = red[0] + red[1] + red[2] + red[3];
    float inv = sum > 0.f ? 1.f / sum : 0.f;
#pragma unroll
    for (int q = 0; q < 4; q++) {
        int j = tid + (q << 8);
        w[((long)row << 10) + j] = f2b(e[q] * inv);
    }
    if (tid == 0) hasnb[row] = sum > 0.f ? 1.f : 0.f;
}

// ---------------------------------------------------------------------------
extern "C" void kernel_launch(void* const* d_in, const int* in_sizes, int n_in,
                              void* d_out, int out_size, void* d_ws, size_t ws_size,
                              hipStream_t stream) {
    const float* feats = (const float*)d_in[0];
    const int*   adj   = (const int*)d_in[1];
    const float* W_ih  = (const float*)d_in[2];
    const float* W_hh  = (const float*)d_in[3];
    const float* b_ih  = (const float*)d_in[4];
    const float* b_hh  = (const float*)d_in[5];
    const float* gx_W1 = (const float*)d_in[6];  const float* gx_b1 = (const float*)d_in[7];
    const float* gx_W2 = (const float*)d_in[8];  const float* gx_b2 = (const float*)d_in[9];
    const float* gz_W1 = (const float*)d_in[10]; const float* gz_b1 = (const float*)d_in[11];
    const float* gz_W2 = (const float*)d_in[12]; const float* gz_b2 = (const float*)d_in[13];
    const float* gv_W1 = (const float*)d_in[14]; const float* gv_b1 = (const float*)d_in[15];
    const float* gv_W2 = (const float*)d_in[16]; const float* gv_b2 = (const float*)d_in[17];
    const float* gn_W1 = (const float*)d_in[18]; const float* gn_b1 = (const float*)d_in[19];
    const float* gn_W2 = (const float*)d_in[20]; const float* gn_b2 = (const float*)d_in[21];
    const float* out_W = (const float*)d_in[22]; const float* out_b = (const float*)d_in[23];

    char* ws = (char*)d_ws;
    size_t off = 0;
    auto alloc = [&](size_t bytes) {
        void* p = ws + off;
        off += (bytes + 255) & ~(size_t)255;
        return p;
    };
    u16* WhhP      = (u16*)alloc(2048L * 512 * 2);
    u16* WihP      = (u16*)alloc(2048L * 256 * 2);
    float* biasP   = (float*)alloc(2048L * 4);
    u64* hx        = (u64*)alloc(2L * 2048 * 8);
    u16* featsB    = (u16*)alloc(8192L * 256 * 2);
    u16* gxW1b     = (u16*)alloc(256L * 512 * 2);
    u16* gxW2b     = (u16*)alloc(256L * 256 * 2);
    u16* gvW1b     = (u16*)alloc(256L * 512 * 2);
    u16* gvW2b     = (u16*)alloc(256L * 256 * 2);
    u16* gzW1b     = (u16*)alloc(256L * 512 * 2);
    u16* gzW2b     = (u16*)alloc(256L * 256 * 2);
    u16* gnW1b     = (u16*)alloc(256L * 256 * 2);
    u16* gnW2b     = (u16*)alloc(256L * 256 * 2);
    u16* outWb     = (u16*)alloc(256L * 768 * 2);
    u16* xproj     = (u16*)alloc(8L * 1024 * 2048 * 2);
    u16* h         = (u16*)alloc(8L * 1024 * 512 * 2);
    u16* hT        = (u16*)alloc(8L * 1024 * 512 * 2);
    u16* t1        = (u16*)alloc(8192L * 256 * 2);
    u16* tB        = (u16*)alloc(8192L * 256 * 2);
    u16* ax        = (u16*)alloc(8192L * 256 * 2);
    u16* av        = (u16*)alloc(8192L * 256 * 2);
    u16* agg       = (u16*)alloc(8192L * 256 * 2);
    float* hasnb   = (float*)alloc(8192L * 4);
    float* scores  = (float*)alloc(8L * 1024 * 1024 * 4);
    u16* w         = (u16*)alloc(8L * 1024 * 1024 * 2);
    if (off > ws_size) return;  // workspace too small -> fail visibly

    hipMemsetAsync(hx, 0, 2L * 2048 * 8, stream);  // deterministic tags
    pack_params<<<2048, 256, 0, stream>>>(W_hh, W_ih, b_ih, b_hh, WhhP, WihP, biasP);

    auto cvt = [&](const float* src, u16* dst, int n) {
        cvt_bf16<<<(n + 1023) / 1024, 256, 0, stream>>>(src, dst, n);
    };
    cvt(feats, featsB, 8192 * 256);
    cvt(gx_W1, gxW1b, 256 * 512);  cvt(gx_W2, gxW2b, 256 * 256);
    cvt(gv_W1, gvW1b, 256 * 512);  cvt(gv_W2, gvW2b, 256 * 256);
    cvt(gz_W1, gzW1b, 256 * 512);  cvt(gz_W2, gzW2b, 256 * 256);
    cvt(gn_W1, gnW1b, 256 * 256);  cvt(gn_W2, gnW2b, 256 * 256);
    cvt(out_W, outWb, 256 * 768);

    // x_proj = feats @ W_ihP^T + (b_ih+b_hh), stored time-major [t][b][p]
    gemm_bt<<<dim3(128, 16, 1), 256, 0, stream>>>(
        featsB, nullptr, 256, WihP, xproj, 8192, 2048, 256, 0, 0, 0,
        biasP, nullptr, GF_XPOSE);

    lstm_rec<<<4, 512, 0, stream>>>(WhhP, xproj, h, hx);

    transpose_h<<<dim3(16, 8, 8), 256, 0, stream>>>(h, hT);

    // ax = mlp(h; gx)
    gemm_bt<<<dim3(128, 2, 1), 256, 0, stream>>>(
        h, nullptr, 512, gxW1b, t1, 8192, 256, 512, 0, 0, 0, gx_b1, nullptr, GF_RELU);
    gemm_bt<<<dim3(128, 2, 1), 256, 0, stream>>>(
        t1, nullptr, 256, gxW2b, ax, 8192, 256, 256, 0, 0, 0, gx_b2, nullptr, 0);
    // av = mlp(h; gv)
    gemm_bt<<<dim3(128, 2, 1), 256, 0, stream>>>(
        h, nullptr, 512, gvW1b, t1, 8192, 256, 512, 0, 0, 0, gv_b1, nullptr, GF_RELU);
    gemm_bt<<<dim3(128, 2, 1), 256, 0, stream>>>(
        t1, nullptr, 256, gvW2b, av, 8192, 256, 256, 0, 0, 0, gv_b2, nullptr, 0);

    // scores[b] = ax[b] @ av[b]^T  (f32)
    gemm_bt<<<dim3(16, 8, 8), 256, 0, stream>>>(
        ax, nullptr, 256, av, scores, 1024, 1024, 256,
        262144, 262144, 1048576, nullptr, nullptr, GF_F32);

    softmax_row<<<8192, 256, 0, stream>>>(scores, adj, w, hasnb);

    // sagg[b] = w[b] @ h[b]  via A=w, B=hT (B^T form); xproj is dead -> reuse
    u16* sagg = xproj;
    gemm_bt<<<dim3(16, 4, 8), 256, 0, stream>>>(
        w, nullptr, 1024, hT, sagg, 1024, 512, 1024,
        1048576, 524288, 524288, nullptr, nullptr, 0);

    // agg = mlp(mlp(sagg; gz); gn) * hasnb
    gemm_bt<<<dim3(128, 2, 1), 256, 0, stream>>>(
        sagg, nullptr, 512, gzW1b, t1, 8192, 256, 512, 0, 0, 0, gz_b1, nullptr, GF_RELU);
    gemm_bt<<<dim3(128, 2, 1), 256, 0, stream>>>(
        t1, nullptr, 256, gzW2b, tB, 8192, 256, 256, 0, 0, 0, gz_b2, nullptr, 0);
    gemm_bt<<<dim3(128, 2, 1), 256, 0, stream>>>(
        tB, nullptr, 256, gnW1b, t1, 8192, 256, 256, 0, 0, 0, gn_b1, nullptr, GF_RELU);
    gemm_bt<<<dim3(128, 2, 1), 256, 0, stream>>>(
        t1, nullptr, 256, gnW2b, agg, 8192, 256, 256, 0, 0, 0, gn_b2, hasnb, 0);

    // out = concat(h, agg) @ out_W^T + out_b  (f32 output)
    gemm_bt<<<dim3(128, 2, 1), 256, 0, stream>>>(
        h, agg, 512, outWb, (float*)d_out, 8192, 256, 768, 0, 0, 0, out_b, nullptr, GF_F32);
}

// Round 11
// 2449.044 us; speedup vs baseline: 2.3626x; 2.3626x over previous
//
#include <hip/hip_runtime.h>

typedef unsigned short u16;
typedef unsigned long long u64;
using short8 = __attribute__((ext_vector_type(8))) short;
using f32x4  = __attribute__((ext_vector_type(4))) float;

#define GF_RELU  1
#define GF_F32   2
#define GF_XPOSE 4

__device__ __forceinline__ float b2f(u16 x) {
    unsigned u = ((unsigned)x) << 16;
    return __builtin_bit_cast(float, u);
}
__device__ __forceinline__ u16 f2b(float f) {
    unsigned u = __builtin_bit_cast(unsigned, f);
    unsigned r = u + 0x7FFFu + ((u >> 16) & 1u);
    return (u16)(r >> 16);
}
__device__ __forceinline__ f32x4 mfma_bf16(uint4 a, uint4 b, f32x4 c) {
    return __builtin_amdgcn_mfma_f32_16x16x32_bf16(
        __builtin_bit_cast(short8, a), __builtin_bit_cast(short8, b), c, 0, 0, 0);
}
__device__ __forceinline__ f32x4 zero4() { f32x4 z = {0.f, 0.f, 0.f, 0.f}; return z; }

// ---------------------------------------------------------------------------
// f32 -> bf16 conversion (grid-stride)
// ---------------------------------------------------------------------------
__global__ __launch_bounds__(256) void cvt_bf16(const float* __restrict__ src,
                                                u16* __restrict__ dst, int n) {
    for (int i = blockIdx.x * 256 + threadIdx.x; i < n; i += gridDim.x * 256)
        dst[i] = f2b(src[i]);
}

// ---------------------------------------------------------------------------
// Pack W_hh / W_ih (f32 in) into unit-major gate order bf16: packed row
// p = unit*4+gate maps to original row gate*512+unit. biasP (f32) = b_ih+b_hh.
// ---------------------------------------------------------------------------
__global__ void pack_params(const float* __restrict__ Whh, const float* __restrict__ Wih,
                            const float* __restrict__ bih, const float* __restrict__ bhh,
                            u16* __restrict__ WhhP, u16* __restrict__ WihP,
                            float* __restrict__ biasP) {
    int p = blockIdx.x;      // 2048
    int t = threadIdx.x;     // 256
    int orig = ((p & 3) << 9) + (p >> 2);
    WhhP[((long)p << 9) + t]       = f2b(Whh[((long)orig << 9) + t]);
    WhhP[((long)p << 9) + 256 + t] = f2b(Whh[((long)orig << 9) + 256 + t]);
    WihP[((long)p << 8) + t]       = f2b(Wih[((long)orig << 8) + t]);
    if (t == 0) biasP[p] = bih[orig] + bhh[orig];
}

// ---------------------------------------------------------------------------
// Generic C = act(A @ B^T + bias) GEMM, 64x128 tile, register-prefetch
// pipeline (tile k+1 global loads issued before tile k MFMAs -> latency
// overlapped; r10-proven: halved the GEMM stack). bf16 in, bf16/f32 out.
// A row-stride = ksplit; k >= ksplit reads A2. GF_XPOSE: x_proj time-major.
// ---------------------------------------------------------------------------
__global__ __launch_bounds__(256) void gemm_bt(
    const u16* __restrict__ A, const u16* __restrict__ A2, int ksplit,
    const u16* __restrict__ B, void* __restrict__ Cout,
    int M, int N, int K,
    long sAb, long sBb, long sCb,
    const float* __restrict__ bias, const float* __restrict__ rowmask, int flags) {
    __shared__ __align__(16) u16 As[64][40];
    __shared__ __align__(16) u16 Bs[128][40];
    const int bz = blockIdx.z;
    const u16* Ab = A + (long)bz * sAb;
    const u16* Bb = B + (long)bz * sBb;
    const int m0 = blockIdx.x << 6, n0 = blockIdx.y << 7;
    const int tid = threadIdx.x;
    const int lane = tid & 63, wave = tid >> 6;
    const int srow = tid >> 2, skc = (tid & 3) << 3;
    const int frm = lane & 15, fq = lane >> 4;

    auto loadA = [&](int ka) -> uint4 {
        const u16* p = (ka < ksplit)
            ? Ab + (long)(m0 + srow) * ksplit + ka
            : A2 + (long)(m0 + srow) * (K - ksplit) + (ka - ksplit);
        return *(const uint4*)p;
    };
    const u16* Brow0 = Bb + (long)(n0 + srow) * K;
    const u16* Brow1 = Bb + (long)(n0 + 64 + srow) * K;

    f32x4 acc[8];
#pragma unroll
    for (int i = 0; i < 8; i++) acc[i] = zero4();

    uint4 a  = loadA(skc);
    uint4 b0 = *(const uint4*)(Brow0 + skc);
    uint4 b1 = *(const uint4*)(Brow1 + skc);

    for (int k0 = 0; k0 < K; k0 += 32) {
        __syncthreads();
        *(uint4*)&As[srow][skc] = a;
        *(uint4*)&Bs[srow][skc] = b0;
        *(uint4*)&Bs[64 + srow][skc] = b1;
        __syncthreads();
        int kn = k0 + 32;
        if (kn < K) {           // prefetch next tile; overlaps MFMAs below
            a  = loadA(kn + skc);
            b0 = *(const uint4*)(Brow0 + kn + skc);
            b1 = *(const uint4*)(Brow1 + kn + skc);
        }
        uint4 af = *(const uint4*)&As[(wave << 4) + frm][fq << 3];
#pragma unroll
        for (int nt = 0; nt < 8; nt++) {
            uint4 bf = *(const uint4*)&Bs[(nt << 4) + frm][fq << 3];
            acc[nt] = mfma_bf16(af, bf, acc[nt]);
        }
    }
#pragma unroll
    for (int nt = 0; nt < 8; nt++) {
        int col = n0 + (nt << 4) + frm;
        float bv = bias ? bias[col] : 0.f;
#pragma unroll
        for (int r = 0; r < 4; r++) {
            int row = m0 + (wave << 4) + (fq << 2) + r;
            float v = acc[nt][r] + bv;
            if (flags & GF_RELU) v = fmaxf(v, 0.f);
            if (rowmask) v *= rowmask[row];
            long orow = (flags & GF_XPOSE) ? (long)((row & 1023) * 8 + (row >> 10))
                                           : (long)row;
            if (flags & GF_F32)
                ((float*)Cout)[(long)bz * sCb + orow * N + col] = v;
            else
                ((u16*)Cout)[(long)bz * sCb + orow * N + col] = f2b(v);
        }
    }
}

// ---------------------------------------------------------------------------
// Persistent LSTM recurrence (r9-proven, 2113 us). 8 WGs x 512 threads
// (8 waves, 1 slice/wave). Slice ws = wg*8+wv owns packed gate-cols
// [ws*32,+32) = units [ws*8,+8). Protocol: tag-in-data u64 atoms {tag=t+1,
// dword=2 bf16}, relaxed agent scope, double-buffered by step parity. Each
// wave polls its own 256-atom portion (4/lane/round). No fences/acks: tag
// rides with payload; parity induction prevents clobber. xproj is [t][b][p].
// NOTE (r7/r10 lesson): bfrag[2][16] = 128 weight-VGPRs/lane is the proven
// allocator maximum; P=4 (256 regs) and P=2 (512) both spill -> 2.5-10x.
// ---------------------------------------------------------------------------
__global__ __launch_bounds__(512, 1) void lstm_rec(
    const u16* __restrict__ WhhP, const u16* __restrict__ xproj,
    u16* __restrict__ h, u64* __restrict__ hx) {
    __shared__ float g_lds[8][260];       // [batch][local gate col 0..255]
    __shared__ unsigned hshare[8][260];   // [batch][h dword 0..255]
    const int wg = blockIdx.x;            // 8
    const int tid = threadIdx.x;          // 512
    const int lane = tid & 63, wv = tid >> 6;     // 8 waves
    const int frm = lane & 15, fq = lane >> 4;
    const int mbb = frm & 7;              // A-operand batch row
    const int xb = (fq & 1) << 2;         // batch base for D rows fq*4+r
    const int ws = (wg << 3) + wv;        // global slice 0..63

    uint4 bfrag[2][16];
#pragma unroll
    for (int T = 0; T < 2; T++)
#pragma unroll
        for (int kk = 0; kk < 16; kk++)
            bfrag[T][kk] = *(const uint4*)&WhhP[((long)((ws << 5) + (T << 4) + frm) << 9) +
                                                (kk << 5) + (fq << 3)];

    float creg = 0.f;                     // cell state for (batch=wv, unit=wg*64+lane)
    int budget = 1 << 21;                 // poll bailout: guarantees termination

#pragma unroll 1
    for (int t = 0; t < 1024; t++) {
        // prefetch x_proj for this step (time-major layout: contiguous block)
        float xp[2][4];
#pragma unroll
        for (int T = 0; T < 2; T++)
#pragma unroll
            for (int r = 0; r < 4; r++)
                xp[T][r] = b2f(xproj[((long)(t * 8 + xb + r) << 11) +
                                     (ws << 5) + (T << 4) + frm]);

        f32x4 acc0 = zero4(), acc1 = zero4();
        if (t > 0) {
            // poll own portion of h(t-1): atoms [wv*256, wv*256+256), 4/lane
            const u64* buf = hx + (((t - 1) & 1) << 11);
            u64 v[4];
            const unsigned want = (unsigned)t;
            while (true) {
#pragma unroll
                for (int j = 0; j < 4; j++)
                    v[j] = __hip_atomic_load(&buf[(wv << 8) + lane + (j << 6)],
                                             __ATOMIC_RELAXED, __HIP_MEMORY_SCOPE_AGENT);
                bool ok = true;
#pragma unroll
                for (int j = 0; j < 4; j++) ok &= ((unsigned)(v[j] >> 32) == want);
                if (__all(ok) || --budget < 0) break;
            }
#pragma unroll
            for (int j = 0; j < 4; j++) {
                int a = (wv << 8) + lane + (j << 6);   // atom = b*256 + d
                hshare[a >> 8][a & 255] = (unsigned)v[j];
            }
            __syncthreads();
            uint4 afr[16];
#pragma unroll
            for (int kk = 0; kk < 16; kk++)
                afr[kk] = *(const uint4*)&hshare[mbb][(kk << 4) + (fq << 2)];
#pragma unroll
            for (int kk = 0; kk < 16; kk++) {
                acc0 = mfma_bf16(afr[kk], bfrag[0][kk], acc0);
                acc1 = mfma_bf16(afr[kk], bfrag[1][kk], acc1);
            }
        }

        // phase 1: gate pre-activations to LDS (wave wv: local cols wv*32..+31)
        if (fq < 2) {
#pragma unroll
            for (int T = 0; T < 2; T++) {
                f32x4 accT = T ? acc1 : acc0;
#pragma unroll
                for (int r = 0; r < 4; r++)
                    g_lds[(fq << 2) + r][(wv << 5) + (T << 4) + frm] = accT[r] + xp[T][r];
            }
        }
        __syncthreads();

        // phase 2: thread (batch=wv, local unit=lane): activations, c-update,
        // then even lanes publish {tag,2xbf16} atoms straight from registers
        {
            f32x4 g = *(const f32x4*)&g_lds[wv][lane << 2];
            float iv = 1.f / (1.f + __expf(-g[0]));
            float fv = 1.f / (1.f + __expf(-g[1]));
            float gv = 1.f - 2.f / (__expf(2.f * g[2]) + 1.f);
            float ov = 1.f / (1.f + __expf(-g[3]));
            creg = fv * creg + iv * gv;
            float hv = ov * (1.f - 2.f / (__expf(2.f * creg) + 1.f));
            float hn = __shfl_down(hv, 1);   // neighbor unit's h
            if (!(lane & 1)) {
                int b = wv, j = lane >> 1;   // dword j covers local units 2j,2j+1
                unsigned dw = (unsigned)f2b(hv) | ((unsigned)f2b(hn) << 16);
                ((unsigned*)h)[(((long)(b * 1024 + t)) << 8) + (wg << 5) + j] = dw;
                u64 pv = ((u64)(unsigned)(t + 1) << 32) | (u64)dw;
                __hip_atomic_store(&hx[((t & 1) << 11) + (b << 8) + (wg << 5) + j], pv,
                                   __ATOMIC_RELAXED, __HIP_MEMORY_SCOPE_AGENT);
            }
        }
        // next iteration's post-poll __syncthreads guards hshare/g_lds reuse
    }
}

// ---------------------------------------------------------------------------
// h [b][t][u] -> hT [b][u][t]
// ---------------------------------------------------------------------------
__global__ __launch_bounds__(256) void transpose_h(const u16* __restrict__ h,
                                                   u16* __restrict__ hT) {
    __shared__ __align__(16) u16 tile[64][72];
    const int b = blockIdx.z;
    const int t0 = blockIdx.x << 6, u0 = blockIdx.y << 6;
    const int tid = threadIdx.x;
    const int r = tid >> 3, c8 = (tid & 7) << 3;
#pragma unroll
    for (int j = 0; j < 2; j++) {
        int row = r + (j << 5);
        *(uint4*)&tile[row][c8] =
            *(const uint4*)&h[(((long)b << 10) + t0 + row) * 512 + u0 + c8];
    }
    __syncthreads();
#pragma unroll
    for (int j = 0; j < 2; j++) {
        int urow = r + (j << 5);
        unsigned wds[4];
#pragma unroll
        for (int k = 0; k < 4; k++) {
            unsigned lo = tile[c8 + (k << 1)][urow];
            unsigned hi = tile[c8 + (k << 1) + 1][urow];
            wds[k] = lo | (hi << 16);
        }
        uint4 v; v.x = wds[0]; v.y = wds[1]; v.z = wds[2]; v.w = wds[3];
        *(uint4*)&hT[(((long)b << 9) + u0 + urow) * 1024 + t0 + c8] = v;
    }
}

// ---------------------------------------------------------------------------
// Masked softmax over rows of scores [8192][1024]; w = softmax*mask (bf16);
// hasnb = 1.0 if any neighbor else 0.0
// ---------------------------------------------------------------------------
__global__ __launch_bounds__(256) void softmax_row(
    const float* __restrict__ scores, const int* __restrict__ adj,
    u16* __restrict__ w, float* __restrict__ hasnb) {
    __shared__ float red[4];
    const int row = blockIdx.x;  // 8192
    const int i = row & 1023;
    const int tid = threadIdx.x;
    const int lane = tid & 63, wave = tid >> 6;
    const float* s = scores + ((long)row << 10);
    const int* arow = adj + ((long)row << 10);

    float sv[4]; bool mk[4];
    float mx = -3.0e38f;
#pragma unroll
    for (int q = 0; q < 4; q++) {
        int j = tid + (q << 8);
        mk[q] = (arow[j] > 0) && (j != i);
        sv[q] = s[j];
        if (mk[q]) mx = fmaxf(mx, sv[q]);
    }
    for (int off = 32; off; off >>= 1) mx = fmaxf(mx, __shfl_xor(mx, off));
    if (lane == 0) red[wave] = mx;
    __syncthreads();
    mx = fmaxf(fmaxf(red[0], red[1]), fmaxf(red[2], red[3]));
    float e[4]; float sum = 0.f;
#pragma unroll
    for (int q = 0; q < 4; q++) {
        e[q] = mk[q] ? __expf(sv[q] - mx) : 0.f;
        sum += e[q];
    }
    __syncthreads();
    for (int off = 32; off; off >>= 1) sum += __shfl_xor(sum, off);
    if (lane == 0) red[wave] = sum;
    __syncthreads();
    sum = red[0] + red[1] + red[2] + red[3];
    float inv = sum > 0.f ? 1.f / sum : 0.f;
#pragma unroll
    for (int q = 0; q < 4; q++) {
        int j = tid + (q << 8);
        w[((long)row << 10) + j] = f2b(e[q] * inv);
    }
    if (tid == 0) hasnb[row] = sum > 0.f ? 1.f : 0.f;
}

// ---------------------------------------------------------------------------
extern "C" void kernel_launch(void* const* d_in, const int* in_sizes, int n_in,
                              void* d_out, int out_size, void* d_ws, size_t ws_size,
                              hipStream_t stream) {
    const float* feats = (const float*)d_in[0];
    const int*   adj   = (const int*)d_in[1];
    const float* W_ih  = (const float*)d_in[2];
    const float* W_hh  = (const float*)d_in[3];
    const float* b_ih  = (const float*)d_in[4];
    const float* b_hh  = (const float*)d_in[5];
    const float* gx_W1 = (const float*)d_in[6];  const float* gx_b1 = (const float*)d_in[7];
    const float* gx_W2 = (const float*)d_in[8];  const float* gx_b2 = (const float*)d_in[9];
    const float* gz_W1 = (const float*)d_in[10]; const float* gz_b1 = (const float*)d_in[11];
    const float* gz_W2 = (const float*)d_in[12]; const float* gz_b2 = (const float*)d_in[13];
    const float* gv_W1 = (const float*)d_in[14]; const float* gv_b1 = (const float*)d_in[15];
    const float* gv_W2 = (const float*)d_in[16]; const float* gv_b2 = (const float*)d_in[17];
    const float* gn_W1 = (const float*)d_in[18]; const float* gn_b1 = (const float*)d_in[19];
    const float* gn_W2 = (const float*)d_in[20]; const float* gn_b2 = (const float*)d_in[21];
    const float* out_W = (const float*)d_in[22]; const float* out_b = (const float*)d_in[23];

    char* ws = (char*)d_ws;
    size_t off = 0;
    auto alloc = [&](size_t bytes) {
        void* p = ws + off;
        off += (bytes + 255) & ~(size_t)255;
        return p;
    };
    u16* WhhP      = (u16*)alloc(2048L * 512 * 2);
    u16* WihP      = (u16*)alloc(2048L * 256 * 2);
    float* biasP   = (float*)alloc(2048L * 4);
    u64* hx        = (u64*)alloc(2L * 2048 * 8);
    u16* featsB    = (u16*)alloc(8192L * 256 * 2);
    u16* gxW1b     = (u16*)alloc(256L * 512 * 2);
    u16* gxW2b     = (u16*)alloc(256L * 256 * 2);
    u16* gvW1b     = (u16*)alloc(256L * 512 * 2);
    u16* gvW2b     = (u16*)alloc(256L * 256 * 2);
    u16* gzW1b     = (u16*)alloc(256L * 512 * 2);
    u16* gzW2b     = (u16*)alloc(256L * 256 * 2);
    u16* gnW1b     = (u16*)alloc(256L * 256 * 2);
    u16* gnW2b     = (u16*)alloc(256L * 256 * 2);
    u16* outWb     = (u16*)alloc(256L * 768 * 2);
    u16* xproj     = (u16*)alloc(8L * 1024 * 2048 * 2);
    u16* h         = (u16*)alloc(8L * 1024 * 512 * 2);
    u16* hT        = (u16*)alloc(8L * 1024 * 512 * 2);
    u16* t1        = (u16*)alloc(8192L * 256 * 2);
    u16* tB        = (u16*)alloc(8192L * 256 * 2);
    u16* ax        = (u16*)alloc(8192L * 256 * 2);
    u16* av        = (u16*)alloc(8192L * 256 * 2);
    u16* agg       = (u16*)alloc(8192L * 256 * 2);
    float* hasnb   = (float*)alloc(8192L * 4);
    float* scores  = (float*)alloc(8L * 1024 * 1024 * 4);
    u16* w         = (u16*)alloc(8L * 1024 * 1024 * 2);
    if (off > ws_size) return;  // workspace too small -> fail visibly

    hipMemsetAsync(hx, 0, 2L * 2048 * 8, stream);  // deterministic tags
    pack_params<<<2048, 256, 0, stream>>>(W_hh, W_ih, b_ih, b_hh, WhhP, WihP, biasP);

    auto cvt = [&](const float* src, u16* dst, int n) {
        cvt_bf16<<<(n + 1023) / 1024, 256, 0, stream>>>(src, dst, n);
    };
    cvt(feats, featsB, 8192 * 256);
    cvt(gx_W1, gxW1b, 256 * 512);  cvt(gx_W2, gxW2b, 256 * 256);
    cvt(gv_W1, gvW1b, 256 * 512);  cvt(gv_W2, gvW2b, 256 * 256);
    cvt(gz_W1, gzW1b, 256 * 512);  cvt(gz_W2, gzW2b, 256 * 256);
    cvt(gn_W1, gnW1b, 256 * 256);  cvt(gn_W2, gnW2b, 256 * 256);
    cvt(out_W, outWb, 256 * 768);

    // x_proj = feats @ W_ihP^T + (b_ih+b_hh), stored time-major [t][b][p]
    gemm_bt<<<dim3(128, 16, 1), 256, 0, stream>>>(
        featsB, nullptr, 256, WihP, xproj, 8192, 2048, 256, 0, 0, 0,
        biasP, nullptr, GF_XPOSE);

    lstm_rec<<<8, 512, 0, stream>>>(WhhP, xproj, h, hx);

    transpose_h<<<dim3(16, 8, 8), 256, 0, stream>>>(h, hT);

    // ax = mlp(h; gx)
    gemm_bt<<<dim3(128, 2, 1), 256, 0, stream>>>(
        h, nullptr, 512, gxW1b, t1, 8192, 256, 512, 0, 0, 0, gx_b1, nullptr, GF_RELU);
    gemm_bt<<<dim3(128, 2, 1), 256, 0, stream>>>(
        t1, nullptr, 256, gxW2b, ax, 8192, 256, 256, 0, 0, 0, gx_b2, nullptr, 0);
    // av = mlp(h; gv)
    gemm_bt<<<dim3(128, 2, 1), 256, 0, stream>>>(
        h, nullptr, 512, gvW1b, t1, 8192, 256, 512, 0, 0, 0, gv_b1, nullptr, GF_RELU);
    gemm_bt<<<dim3(128, 2, 1), 256, 0, stream>>>(
        t1, nullptr, 256, gvW2b, av, 8192, 256, 256, 0, 0, 0, gv_b2, nullptr, 0);

    // scores[b] = ax[b] @ av[b]^T  (f32)
    gemm_bt<<<dim3(16, 8, 8), 256, 0, stream>>>(
        ax, nullptr, 256, av, scores, 1024, 1024, 256,
        262144, 262144, 1048576, nullptr, nullptr, GF_F32);

    softmax_row<<<8192, 256, 0, stream>>>(scores, adj, w, hasnb);

    // sagg[b] = w[b] @ h[b]  via A=w, B=hT (B^T form); xproj is dead -> reuse
    u16* sagg = xproj;
    gemm_bt<<<dim3(16, 4, 8), 256, 0, stream>>>(
        w, nullptr, 1024, hT, sagg, 1024, 512, 1024,
        1048576, 524288, 524288, nullptr, nullptr, 0);

    // agg = mlp(mlp(sagg; gz); gn) * hasnb
    gemm_bt<<<dim3(128, 2, 1), 256, 0, stream>>>(
        sagg, nullptr, 512, gzW1b, t1, 8192, 256, 512, 0, 0, 0, gz_b1, nullptr, GF_RELU);
    gemm_bt<<<dim3(128, 2, 1), 256, 0, stream>>>(
        t1, nullptr, 256, gzW2b, tB, 8192, 256, 256, 0, 0, 0, gz_b2, nullptr, 0);
    gemm_bt<<<dim3(128, 2, 1), 256, 0, stream>>>(
        tB, nullptr, 256, gnW1b, t1, 8192, 256, 256, 0, 0, 0, gn_b1, nullptr, GF_RELU);
    gemm_bt<<<dim3(128, 2, 1), 256, 0, stream>>>(
        t1, nullptr, 256, gnW2b, agg, 8192, 256, 256, 0, 0, 0, gn_b2, hasnb, 0);

    // out = concat(h, agg) @ out_W^T + out_b  (f32 output)
    gemm_bt<<<dim3(128, 2, 1), 256, 0, stream>>>(
        h, agg, 512, outWb, (float*)d_out, 8192, 256, 768, 0, 0, 0, out_b, nullptr, GF_F32);
}